// Round 1
// baseline (2764.012 us; speedup 1.0000x reference)
//
#include <hip/hip_runtime.h>

#define CH 16
#define HID 128
#define KOUT 15
#define NB 8
#define NH 256
#define NW 256
#define NPX (NB*NH*NW)
#define NSTEP 10
#define TILE 16
#define HALO 3
#define TW (TILE+2*HALO)
#define LDSSTRIDE 20
#define STEPSTATS 1536

__device__ __forceinline__ int refl(int i, int n){
    if (i < 0) i = -i;
    if (i >= n) i = 2*n - 2 - i;
    return i;
}

// repack conv weights (16,1,7,7) -> wp[tap][c]; fc1 (15,128) -> f1t[o][k] (k padded to 16)
__global__ void k_repack(const float* __restrict__ cw, const float* __restrict__ f1,
                         float* __restrict__ wp, float* __restrict__ f1t){
    int t = blockIdx.x*256 + threadIdx.x;
    if (t < 49*16){ int tap = t >> 4, c = t & 15; wp[tap*16 + c] = cw[c*49 + tap]; }
    if (t < 128*16){ int o = t >> 4, k = t & 15; f1t[o*16 + k] = (k < KOUT) ? f1[k*HID + o] : 0.f; }
}

__global__ void k_zero(float* __restrict__ p, int n){
    int t = blockIdx.x*256 + threadIdx.x;
    if (t < n) p[t] = 0.f;
}

// depthwise 7x7 conv with reflect padding, NHWC state -> d (bias included)
__global__ __launch_bounds__(256)
void k_conv(const float* __restrict__ st, const float* __restrict__ wp,
            const float* __restrict__ cb, float* __restrict__ dout){
    __shared__ float lds[TW*TW*LDSSTRIDE];
    const int b = blockIdx.z;
    const int y0 = blockIdx.y*TILE, x0 = blockIdx.x*TILE;
    const int t = threadIdx.x;
    for (int i = t; i < TW*TW*4; i += 256){
        int slot = i >> 2, q = i & 3;
        int py = slot / TW, px = slot - py*TW;
        int gy = refl(y0 + py - HALO, NH);
        int gx = refl(x0 + px - HALO, NW);
        float4 v = *(const float4*)&st[(((size_t)b*NH + gy)*NW + gx)*CH + 4*q];
        *(float4*)&lds[slot*LDSSTRIDE + 4*q] = v;
    }
    __syncthreads();
    const int tx = t & 15, ty = t >> 4;
    float4 acc[4];
    #pragma unroll
    for (int q = 0; q < 4; ++q)
        acc[q] = *(const float4*)&cb[4*q];
    for (int dy = 0; dy < 7; ++dy){
        #pragma unroll
        for (int dx = 0; dx < 7; ++dx){
            const int base = ((ty+dy)*TW + (tx+dx))*LDSSTRIDE;
            const float* wrow = &wp[(dy*7+dx)*16];
            #pragma unroll
            for (int q = 0; q < 4; ++q){
                float4 w4 = *(const float4*)&wrow[4*q];
                float4 v  = *(const float4*)&lds[base + 4*q];
                acc[q].x += w4.x*v.x; acc[q].y += w4.y*v.y;
                acc[q].z += w4.z*v.z; acc[q].w += w4.w*v.w;
            }
        }
    }
    size_t p = ((size_t)b*NH + (size_t)(y0+ty))*NW + (x0+tx);
    #pragma unroll
    for (int q = 0; q < 4; ++q)
        *(float4*)&dout[p*CH + 4*q] = acc[q];
}

// raw second moments of cat = [state, d]: S[32x32] and su[32] (at S+1024)
// thread t: 4x4 tile (I,J) of S, pixel-group g; 64-lane waves share p -> L1 broadcast
__global__ __launch_bounds__(256)
void k_stats(const float* __restrict__ st, const float* __restrict__ dv,
             float* __restrict__ S){
    __shared__ float red[256*20];
    const int t = threadIdx.x;
    const int I = (t >> 3) & 7, J = t & 7, g = t >> 6;
    const float* baseA = (I < 4) ? (st + 4*I) : (dv + 4*(I-4));
    const float* baseB = (J < 4) ? (st + 4*J) : (dv + 4*(J-4));
    float a[4][4];
    #pragma unroll
    for (int i=0;i<4;++i){
        #pragma unroll
        for (int j=0;j<4;++j) a[i][j]=0.f;
    }
    float s4[4] = {0.f,0.f,0.f,0.f};
    const int CHUNK = NPX / 512;
    int p0 = blockIdx.x*CHUNK + g*(CHUNK/4);
    const float* pa = baseA + (size_t)p0*CH;
    const float* pb = baseB + (size_t)p0*CH;
    for (int it = 0; it < CHUNK/4; ++it){
        float4 va = *(const float4*)pa;
        float4 vb = *(const float4*)pb;
        pa += CH; pb += CH;
        float av[4] = {va.x,va.y,va.z,va.w};
        float bv[4] = {vb.x,vb.y,vb.z,vb.w};
        #pragma unroll
        for (int i=0;i<4;++i){
            #pragma unroll
            for (int j=0;j<4;++j) a[i][j] += av[i]*bv[j];
        }
        s4[0]+=av[0]; s4[1]+=av[1]; s4[2]+=av[2]; s4[3]+=av[3];
    }
    #pragma unroll
    for (int i=0;i<16;++i) red[t*20+i] = a[i>>2][i&3];
    #pragma unroll
    for (int i=0;i<4;++i) red[t*20+16+i] = s4[i];
    __syncthreads();
    if (g == 0){
        #pragma unroll
        for (int i=0;i<16;++i){
            float r = red[t*20+i] + red[(t+64)*20+i] + red[(t+128)*20+i] + red[(t+192)*20+i];
            atomicAdd(&S[(4*I + (i>>2))*32 + 4*J + (i&3)], r);
        }
        if (I == J){
            #pragma unroll
            for (int i=0;i<4;++i){
                float r = red[t*20+16+i] + red[(t+64)*20+16+i] + red[(t+128)*20+16+i] + red[(t+192)*20+16+i];
                atomicAdd(&S[1024 + 4*I + i], r);
            }
        }
    }
}

// per-hidden-channel BN scale/shift from moments: mean=w.mu+b0, var=wSw/N-(w.mu/N)^2
__global__ void k_finalize(const float* __restrict__ S,
                           const float* __restrict__ w0, const float* __restrict__ b0,
                           const float* __restrict__ gam, const float* __restrict__ bet,
                           float* __restrict__ sc, float* __restrict__ sh){
    int o = threadIdx.x;
    const float inv = 1.f / (float)NPX;
    float w[32];
    #pragma unroll
    for (int c=0;c<32;++c) w[c] = w0[o*32+c];
    const float* su = S + 1024;
    float m1 = 0.f;
    #pragma unroll
    for (int c=0;c<32;++c) m1 += w[c]*su[c];
    m1 *= inv;
    float q = 0.f;
    for (int i=0;i<32;++i){
        float ti = 0.f;
        #pragma unroll
        for (int j=0;j<32;++j) ti += S[i*32+j]*w[j];
        q += w[i]*ti;
    }
    q *= inv;
    float var = q - m1*m1;
    float rstd = rsqrtf(var + 1e-5f);
    float mean = m1 + b0[o];
    float scale = rstd * gam[o];
    sc[o] = scale;
    sh[o] = bet[o] + (b0[o] - mean)*scale;
}

// main update: fc0 -> BN(scale,shift) -> relu -> fc1 -> masked residual
__global__ __launch_bounds__(256)
void k_update(const float* __restrict__ st, const float* __restrict__ dv,
              const int* __restrict__ msk, const float* __restrict__ w0,
              const float* __restrict__ sc, const float* __restrict__ sh,
              const float* __restrict__ f1t, float* __restrict__ out){
    const size_t p = (size_t)blockIdx.x*256 + threadIdx.x;
    float cat[32];
    #pragma unroll
    for (int q=0;q<4;++q){
        float4 v = *(const float4*)&st[p*CH + 4*q];
        cat[4*q]=v.x; cat[4*q+1]=v.y; cat[4*q+2]=v.z; cat[4*q+3]=v.w;
    }
    #pragma unroll
    for (int q=0;q<4;++q){
        float4 v = *(const float4*)&dv[p*CH + 4*q];
        cat[16+4*q]=v.x; cat[16+4*q+1]=v.y; cat[16+4*q+2]=v.z; cat[16+4*q+3]=v.w;
    }
    float del[KOUT];
    #pragma unroll
    for (int k=0;k<KOUT;++k) del[k]=0.f;
    #pragma unroll 4
    for (int o=0;o<HID;++o){
        float h = 0.f;
        #pragma unroll
        for (int c4=0;c4<8;++c4){
            float4 w4 = *(const float4*)&w0[o*32 + 4*c4];
            h += w4.x*cat[4*c4] + w4.y*cat[4*c4+1] + w4.z*cat[4*c4+2] + w4.w*cat[4*c4+3];
        }
        float hn = fmaxf(h*sc[o] + sh[o], 0.f);
        float fv[16];
        #pragma unroll
        for (int q=0;q<4;++q){
            float4 v = *(const float4*)&f1t[o*16 + 4*q];
            fv[4*q]=v.x; fv[4*q+1]=v.y; fv[4*q+2]=v.z; fv[4*q+3]=v.w;
        }
        #pragma unroll
        for (int k=0;k<KOUT;++k) del[k] += hn*fv[k];
    }
    const float m = (float)msk[p];
    float ov[16];
    ov[0] = cat[0];
    #pragma unroll
    for (int k=0;k<KOUT;++k) ov[k+1] = cat[k+1] + del[k]*m;
    #pragma unroll
    for (int q=0;q<4;++q)
        *(float4*)&out[p*CH + 4*q] = make_float4(ov[4*q],ov[4*q+1],ov[4*q+2],ov[4*q+3]);
}

extern "C" void kernel_launch(void* const* d_in, const int* in_sizes, int n_in,
                              void* d_out, int out_size, void* d_ws, size_t ws_size,
                              hipStream_t stream){
    const float* x   = (const float*)d_in[0];
    const int*   mk  = (const int*)d_in[1];
    const float* cw  = (const float*)d_in[2];
    const float* cb  = (const float*)d_in[3];
    const float* w0  = (const float*)d_in[4];
    const float* b0  = (const float*)d_in[5];
    const float* f1  = (const float*)d_in[6];
    const float* gam = (const float*)d_in[7];
    const float* bet = (const float*)d_in[8];

    float* ws    = (float*)d_ws;
    float* dbuf  = ws;                         // NPX*CH floats
    float* sbuf  = ws + (size_t)NPX*CH;        // NPX*CH floats
    float* stats = ws + (size_t)2*NPX*CH;      // NSTEP*STEPSTATS floats
    float* wp    = stats + NSTEP*STEPSTATS;    // 800 floats
    float* f1t   = wp + 800;                   // 2048 floats

    k_repack<<<8,256,0,stream>>>(cw, f1, wp, f1t);
    k_zero<<<(NSTEP*STEPSTATS+255)/256,256,0,stream>>>(stats, NSTEP*STEPSTATS);

    const float* cur = x;
    float* outp = (float*)d_out;
    for (int s=0;s<NSTEP;++s){
        float* S  = stats + (size_t)s*STEPSTATS;
        float* sc = S + 1056;
        float* sh = S + 1184;
        float* nxt = (s & 1) ? outp : sbuf;    // s=9 lands in d_out
        k_conv<<<dim3(NW/TILE,NH/TILE,NB),256,0,stream>>>(cur, wp, cb, dbuf);
        k_stats<<<512,256,0,stream>>>(cur, dbuf, S);
        k_finalize<<<1,128,0,stream>>>(S, w0, b0, gam, bet, sc, sh);
        k_update<<<NPX/256,256,0,stream>>>(cur, dbuf, mk + (size_t)s*NPX, w0, sc, sh, f1t, nxt);
        cur = nxt;
    }
}

// Round 2
// 1983.472 us; speedup vs baseline: 1.3935x; 1.3935x over previous
//
#include <hip/hip_runtime.h>

#define CH 16
#define HID 128
#define NB 8
#define NH 256
#define NW 256
#define NPX (NB*NH*NW)
#define NSTEP 10
#define TILE 16
#define HALO 3
#define TW (TILE+2*HALO)
#define CSTR 10
#define STEPSTATS 1536
#define GPW 8

typedef __attribute__((ext_vector_type(8))) short short8v;
typedef __attribute__((ext_vector_type(4))) float f32x4;

__device__ __forceinline__ int refl(int i, int n){
    if (i < 0) i = -i;
    if (i >= n) i = 2*n - 2 - i;
    return i;
}

__device__ __forceinline__ unsigned short f2bf(float x){
    unsigned int u = __float_as_uint(x);
    u += 0x7FFFu + ((u >> 16) & 1u);
    return (unsigned short)(u >> 16);
}
__device__ __forceinline__ float bf2f(unsigned short h){
    return __uint_as_float(((unsigned int)h) << 16);
}

// wp[tap][c]; b0 frags: [n][lane][i] for W0^T tiles; b1 frags: [t][lane][i] for F1^T (col0 = 0 pad)
__global__ void k_repack(const float* __restrict__ cw, const float* __restrict__ f1,
                         const float* __restrict__ w0, float* __restrict__ wp,
                         unsigned short* __restrict__ b0h, unsigned short* __restrict__ b0l,
                         unsigned short* __restrict__ b1h, unsigned short* __restrict__ b1l){
    int t = blockIdx.x*256 + threadIdx.x;
    if (t < 49*16){ int tap = t >> 4, c = t & 15; wp[tap*16 + c] = cw[c*49 + tap]; }
    if (t < 4096){
        int n = t >> 9, l = (t >> 3) & 63, i = t & 7;
        int o = 16*n + (l & 15), k = ((l >> 4) << 3) + i;
        float v = w0[o*32 + k];
        unsigned short hi = f2bf(v);
        b0h[t] = hi;
        b0l[t] = f2bf(v - bf2f(hi));
    }
    if (t < 2048){
        int tk = t >> 9, l = (t >> 3) & 63, i = t & 7;
        int c = l & 15, k = tk*32 + ((l >> 4) << 3) + i;
        float v = (c >= 1) ? f1[(c-1)*HID + k] : 0.f;
        unsigned short hi = f2bf(v);
        b1h[t] = hi;
        b1l[t] = f2bf(v - bf2f(hi));
    }
}

__global__ void k_zero(float* __restrict__ p, int n){
    int t = blockIdx.x*256 + threadIdx.x;
    if (t < n) p[t] = 0.f;
}

// depthwise 7x7 conv, reflect pad, 8-channel half per block (z = b*2 + half)
__global__ __launch_bounds__(256)
void k_conv(const float* __restrict__ st, const float* __restrict__ wp,
            const float* __restrict__ cb, float* __restrict__ dout){
    __shared__ float lds[TW*TW*CSTR];
    const int b = blockIdx.z >> 1, half = blockIdx.z & 1;
    const int y0 = blockIdx.y*TILE, x0 = blockIdx.x*TILE;
    const int t = threadIdx.x;
    const int co = half*8;
    for (int i = t; i < TW*TW*2; i += 256){
        int slot = i >> 1, q = i & 1;
        int py = slot / TW, px = slot - py*TW;
        int gy = refl(y0 + py - HALO, NH);
        int gx = refl(x0 + px - HALO, NW);
        float4 v = *(const float4*)&st[(((size_t)b*NH + gy)*NW + gx)*CH + co + 4*q];
        *(float4*)&lds[slot*CSTR + 4*q] = v;
    }
    __syncthreads();
    const int tx = t & 15, ty = t >> 4;
    float4 acc[2];
    #pragma unroll
    for (int q = 0; q < 2; ++q)
        acc[q] = *(const float4*)&cb[co + 4*q];
    for (int dy = 0; dy < 7; ++dy){
        #pragma unroll
        for (int dx = 0; dx < 7; ++dx){
            const int base = ((ty+dy)*TW + (tx+dx))*CSTR;
            const float* wrow = &wp[(dy*7+dx)*16 + co];
            #pragma unroll
            for (int q = 0; q < 2; ++q){
                float4 w4 = *(const float4*)&wrow[4*q];
                float4 v  = *(const float4*)&lds[base + 4*q];
                acc[q].x += w4.x*v.x; acc[q].y += w4.y*v.y;
                acc[q].z += w4.z*v.z; acc[q].w += w4.w*v.w;
            }
        }
    }
    size_t p = ((size_t)b*NH + (size_t)(y0+ty))*NW + (x0+tx);
    #pragma unroll
    for (int q = 0; q < 2; ++q)
        *(float4*)&dout[p*CH + co + 4*q] = acc[q];
}

// raw second moments of cat = [state, d]: S[32x32] and su[32] (at S+1024)
__global__ __launch_bounds__(256)
void k_stats(const float* __restrict__ st, const float* __restrict__ dv,
             float* __restrict__ S){
    __shared__ float red[256*20];
    const int t = threadIdx.x;
    const int I = (t >> 3) & 7, J = t & 7, g = t >> 6;
    const float* baseA = (I < 4) ? (st + 4*I) : (dv + 4*(I-4));
    const float* baseB = (J < 4) ? (st + 4*J) : (dv + 4*(J-4));
    float a[4][4];
    #pragma unroll
    for (int i=0;i<4;++i){
        #pragma unroll
        for (int j=0;j<4;++j) a[i][j]=0.f;
    }
    float s4[4] = {0.f,0.f,0.f,0.f};
    const int CHUNK = NPX / 512;
    int p0 = blockIdx.x*CHUNK + g*(CHUNK/4);
    const float* pa = baseA + (size_t)p0*CH;
    const float* pb = baseB + (size_t)p0*CH;
    for (int it = 0; it < CHUNK/4; ++it){
        float4 va = *(const float4*)pa;
        float4 vb = *(const float4*)pb;
        pa += CH; pb += CH;
        float av[4] = {va.x,va.y,va.z,va.w};
        float bv[4] = {vb.x,vb.y,vb.z,vb.w};
        #pragma unroll
        for (int i=0;i<4;++i){
            #pragma unroll
            for (int j=0;j<4;++j) a[i][j] += av[i]*bv[j];
        }
        s4[0]+=av[0]; s4[1]+=av[1]; s4[2]+=av[2]; s4[3]+=av[3];
    }
    #pragma unroll
    for (int i=0;i<16;++i) red[t*20+i] = a[i>>2][i&3];
    #pragma unroll
    for (int i=0;i<4;++i) red[t*20+16+i] = s4[i];
    __syncthreads();
    if (g == 0){
        #pragma unroll
        for (int i=0;i<16;++i){
            float r = red[t*20+i] + red[(t+64)*20+i] + red[(t+128)*20+i] + red[(t+192)*20+i];
            atomicAdd(&S[(4*I + (i>>2))*32 + 4*J + (i&3)], r);
        }
        if (I == J){
            #pragma unroll
            for (int i=0;i<4;++i){
                float r = red[t*20+16+i] + red[(t+64)*20+16+i] + red[(t+128)*20+16+i] + red[(t+192)*20+16+i];
                atomicAdd(&S[1024 + 4*I + i], r);
            }
        }
    }
}

__global__ void k_finalize(const float* __restrict__ S,
                           const float* __restrict__ w0, const float* __restrict__ b0,
                           const float* __restrict__ gam, const float* __restrict__ bet,
                           float* __restrict__ sc, float* __restrict__ sh){
    int o = threadIdx.x;
    const float inv = 1.f / (float)NPX;
    float w[32];
    #pragma unroll
    for (int c=0;c<32;++c) w[c] = w0[o*32+c];
    const float* su = S + 1024;
    float m1 = 0.f;
    #pragma unroll
    for (int c=0;c<32;++c) m1 += w[c]*su[c];
    m1 *= inv;
    float q = 0.f;
    for (int i=0;i<32;++i){
        float ti = 0.f;
        #pragma unroll
        for (int j=0;j<32;++j) ti += S[i*32+j]*w[j];
        q += w[i]*ti;
    }
    q *= inv;
    float var = q - m1*m1;
    float rstd = rsqrtf(var + 1e-5f);
    float mean = m1 + b0[o];
    float scale = rstd * gam[o];
    sc[o] = scale;
    sh[o] = bet[o] + (b0[o] - mean)*scale;
}

// MFMA update: fc0 (hi/lo split bf16) -> BN/relu -> LDS transpose -> fc1 -> masked residual
__global__ __launch_bounds__(256)
void k_update(const float* __restrict__ st, const float* __restrict__ dv,
              const int* __restrict__ msk,
              const unsigned short* __restrict__ gb0h, const unsigned short* __restrict__ gb0l,
              const unsigned short* __restrict__ gb1h, const unsigned short* __restrict__ gb1l,
              const float* __restrict__ sc, const float* __restrict__ sh,
              float* __restrict__ out){
    __shared__ float hbuf[4*16*132];
    const int lane = threadIdx.x & 63, w = threadIdx.x >> 6;
    const int lo16 = lane & 15, qw = lane >> 4;
    float* hb = &hbuf[w*16*132];

    const short8v* p0h = (const short8v*)gb0h;
    const short8v* p0l = (const short8v*)gb0l;
    const short8v* p1h = (const short8v*)gb1h;
    const short8v* p1l = (const short8v*)gb1l;
    short8v B0h[8], B0l[8], B1h[4], B1l[4];
    #pragma unroll
    for (int n=0;n<8;++n){ B0h[n] = p0h[n*64 + lane]; B0l[n] = p0l[n*64 + lane]; }
    #pragma unroll
    for (int tt=0;tt<4;++tt){ B1h[tt] = p1h[tt*64 + lane]; B1l[tt] = p1l[tt*64 + lane]; }
    float scr[8], shr[8];
    #pragma unroll
    for (int n=0;n<8;++n){ scr[n] = sc[16*n + lo16]; shr[n] = sh[16*n + lo16]; }

    const int gw = blockIdx.x*4 + w;
    const float* abase = (qw < 2) ? st : dv;
    const int choff = (qw & 1)*8;

    for (int gi = 0; gi < GPW; ++gi){
        const size_t pg0 = ((size_t)gw*GPW + gi)*16;
        // --- GEMM1 A fragment: cat[16px x 32ch] hi/lo ---
        const float* ap = abase + (pg0 + lo16)*CH + choff;
        float4 v0 = *(const float4*)ap;
        float4 v1 = *(const float4*)(ap + 4);
        float av[8] = {v0.x,v0.y,v0.z,v0.w,v1.x,v1.y,v1.z,v1.w};
        short8v ah, al;
        #pragma unroll
        for (int i=0;i<8;++i){
            unsigned short hi = f2bf(av[i]);
            ah[i] = (short)hi;
            al[i] = (short)f2bf(av[i] - bf2f(hi));
        }
        f32x4 acc[8];
        #pragma unroll
        for (int n=0;n<8;++n) acc[n] = (f32x4){0.f,0.f,0.f,0.f};
        #pragma unroll
        for (int n=0;n<8;++n){
            acc[n] = __builtin_amdgcn_mfma_f32_16x16x32_bf16(ah, B0h[n], acc[n], 0,0,0);
            acc[n] = __builtin_amdgcn_mfma_f32_16x16x32_bf16(al, B0h[n], acc[n], 0,0,0);
            acc[n] = __builtin_amdgcn_mfma_f32_16x16x32_bf16(ah, B0l[n], acc[n], 0,0,0);
        }
        // --- BN + relu, write C-layout -> LDS [px][hid] (stride 132) ---
        #pragma unroll
        for (int n=0;n<8;++n){
            #pragma unroll
            for (int r=0;r<4;++r){
                float hp = fmaxf(acc[n][r]*scr[n] + shr[n], 0.f);
                hb[(qw*4 + r)*132 + 16*n + lo16] = hp;
            }
        }
        // --- GEMM2: delta[16px x 16c] (col0 zero-padded) ---
        f32x4 dacc = (f32x4){0.f,0.f,0.f,0.f};
        #pragma unroll
        for (int tt=0;tt<4;++tt){
            const float* rp = &hb[lo16*132 + qw*8 + 32*tt];
            float4 h0 = *(const float4*)rp;
            float4 h1 = *(const float4*)(rp + 4);
            float hv[8] = {h0.x,h0.y,h0.z,h0.w,h1.x,h1.y,h1.z,h1.w};
            short8v ah2, al2;
            #pragma unroll
            for (int i=0;i<8;++i){
                unsigned short hi = f2bf(hv[i]);
                ah2[i] = (short)hi;
                al2[i] = (short)f2bf(hv[i] - bf2f(hi));
            }
            dacc = __builtin_amdgcn_mfma_f32_16x16x32_bf16(ah2, B1h[tt], dacc, 0,0,0);
            dacc = __builtin_amdgcn_mfma_f32_16x16x32_bf16(al2, B1h[tt], dacc, 0,0,0);
            dacc = __builtin_amdgcn_mfma_f32_16x16x32_bf16(ah2, B1l[tt], dacc, 0,0,0);
        }
        // --- epilogue: masked residual; col0 delta == 0 keeps const channel exact ---
        #pragma unroll
        for (int r=0;r<4;++r){
            const size_t p = pg0 + qw*4 + r;
            float stv = st[p*CH + lo16];
            float m = (float)msk[p];
            out[p*CH + lo16] = stv + dacc[r]*m;
        }
    }
}

extern "C" void kernel_launch(void* const* d_in, const int* in_sizes, int n_in,
                              void* d_out, int out_size, void* d_ws, size_t ws_size,
                              hipStream_t stream){
    const float* x   = (const float*)d_in[0];
    const int*   mk  = (const int*)d_in[1];
    const float* cw  = (const float*)d_in[2];
    const float* cb  = (const float*)d_in[3];
    const float* w0  = (const float*)d_in[4];
    const float* b0  = (const float*)d_in[5];
    const float* f1  = (const float*)d_in[6];
    const float* gam = (const float*)d_in[7];
    const float* bet = (const float*)d_in[8];

    float* ws    = (float*)d_ws;
    float* dbuf  = ws;                          // NPX*CH
    float* sbuf  = ws + (size_t)NPX*CH;         // NPX*CH
    float* stats = ws + (size_t)2*NPX*CH;       // NSTEP*STEPSTATS
    float* wp    = stats + NSTEP*STEPSTATS;     // 800
    unsigned short* b0h = (unsigned short*)(wp + 800);
    unsigned short* b0l = b0h + 4096;
    unsigned short* b1h = b0l + 4096;
    unsigned short* b1l = b1h + 2048;

    k_repack<<<16,256,0,stream>>>(cw, f1, w0, wp, b0h, b0l, b1h, b1l);
    k_zero<<<(NSTEP*STEPSTATS+255)/256,256,0,stream>>>(stats, NSTEP*STEPSTATS);

    const float* cur = x;
    float* outp = (float*)d_out;
    for (int s=0;s<NSTEP;++s){
        float* S  = stats + (size_t)s*STEPSTATS;
        float* sc = S + 1056;
        float* sh = S + 1184;
        float* nxt = (s & 1) ? outp : sbuf;     // s=9 lands in d_out
        k_conv<<<dim3(NW/TILE,NH/TILE,NB*2),256,0,stream>>>(cur, wp, cb, dbuf);
        k_stats<<<512,256,0,stream>>>(cur, dbuf, S);
        k_finalize<<<1,128,0,stream>>>(S, w0, b0, gam, bet, sc, sh);
        k_update<<<NPX/16/4/GPW,256,0,stream>>>(cur, dbuf, mk + (size_t)s*NPX,
                                                b0h, b0l, b1h, b1l, sc, sh, nxt);
        cur = nxt;
    }
}

// Round 3
// 1515.948 us; speedup vs baseline: 1.8233x; 1.3084x over previous
//
#include <hip/hip_runtime.h>

#define CH 16
#define HID 128
#define NB 8
#define NH 256
#define NW 256
#define NPX (NB*NH*NW)
#define NSTEP 10
#define TILE 16
#define HALO 3
#define TW (TILE+2*HALO)
#define CSTR 10
#define STEPSTATS 1536
#define GPW 8
#define KPW 4
#define SLAB 1280

typedef __attribute__((ext_vector_type(8))) short short8v;
typedef __attribute__((ext_vector_type(4))) float f32x4;

__device__ __forceinline__ int refl(int i, int n){
    if (i < 0) i = -i;
    if (i >= n) i = 2*n - 2 - i;
    return i;
}

__device__ __forceinline__ unsigned short f2bf(float x){
    unsigned int u = __float_as_uint(x);
    u += 0x7FFFu + ((u >> 16) & 1u);
    return (unsigned short)(u >> 16);
}
__device__ __forceinline__ float bf2f(unsigned short h){
    return __uint_as_float(((unsigned int)h) << 16);
}

// wp[tap][c]; b0 frags: [n][lane][i] for W0^T tiles; b1 frags: [t][lane][i] for F1^T (col0 = 0 pad)
__global__ void k_repack(const float* __restrict__ cw, const float* __restrict__ f1,
                         const float* __restrict__ w0, float* __restrict__ wp,
                         unsigned short* __restrict__ b0h, unsigned short* __restrict__ b0l,
                         unsigned short* __restrict__ b1h, unsigned short* __restrict__ b1l){
    int t = blockIdx.x*256 + threadIdx.x;
    if (t < 49*16){ int tap = t >> 4, c = t & 15; wp[tap*16 + c] = cw[c*49 + tap]; }
    if (t < 4096){
        int n = t >> 9, l = (t >> 3) & 63, i = t & 7;
        int o = 16*n + (l & 15), k = ((l >> 4) << 3) + i;
        float v = w0[o*32 + k];
        unsigned short hi = f2bf(v);
        b0h[t] = hi;
        b0l[t] = f2bf(v - bf2f(hi));
    }
    if (t < 2048){
        int tk = t >> 9, l = (t >> 3) & 63, i = t & 7;
        int c = l & 15, k = tk*32 + ((l >> 4) << 3) + i;
        float v = (c >= 1) ? f1[(c-1)*HID + k] : 0.f;
        unsigned short hi = f2bf(v);
        b1h[t] = hi;
        b1l[t] = f2bf(v - bf2f(hi));
    }
}

__global__ void k_zero(float* __restrict__ p, int n){
    int t = blockIdx.x*256 + threadIdx.x;
    if (t < n) p[t] = 0.f;
}

// depthwise 7x7 conv, reflect pad, 8-channel half per block (z = b*2 + half)
__global__ __launch_bounds__(256)
void k_conv(const float* __restrict__ st, const float* __restrict__ wp,
            const float* __restrict__ cb, float* __restrict__ dout){
    __shared__ float lds[TW*TW*CSTR];
    const int b = blockIdx.z >> 1, half = blockIdx.z & 1;
    const int y0 = blockIdx.y*TILE, x0 = blockIdx.x*TILE;
    const int t = threadIdx.x;
    const int co = half*8;
    for (int i = t; i < TW*TW*2; i += 256){
        int slot = i >> 1, q = i & 1;
        int py = slot / TW, px = slot - py*TW;
        int gy = refl(y0 + py - HALO, NH);
        int gx = refl(x0 + px - HALO, NW);
        float4 v = *(const float4*)&st[(((size_t)b*NH + gy)*NW + gx)*CH + co + 4*q];
        *(float4*)&lds[slot*CSTR + 4*q] = v;
    }
    __syncthreads();
    const int tx = t & 15, ty = t >> 4;
    float4 acc[2];
    #pragma unroll
    for (int q = 0; q < 2; ++q)
        acc[q] = *(const float4*)&cb[co + 4*q];
    for (int dy = 0; dy < 7; ++dy){
        #pragma unroll
        for (int dx = 0; dx < 7; ++dx){
            const int base = ((ty+dy)*TW + (tx+dx))*CSTR;
            const float* wrow = &wp[(dy*7+dx)*16 + co];
            #pragma unroll
            for (int q = 0; q < 2; ++q){
                float4 w4 = *(const float4*)&wrow[4*q];
                float4 v  = *(const float4*)&lds[base + 4*q];
                acc[q].x += w4.x*v.x; acc[q].y += w4.y*v.y;
                acc[q].z += w4.z*v.z; acc[q].w += w4.w*v.w;
            }
        }
    }
    size_t p = ((size_t)b*NH + (size_t)(y0+ty))*NW + (x0+tx);
    #pragma unroll
    for (int q = 0; q < 2; ++q)
        *(float4*)&dout[p*CH + co + 4*q] = acc[q];
}

// MFMA second moments: S = cat^T cat over pixels (3 unique 16x16 tiles, hi/lo split)
// plus channel sums via ones-row A-fragment. One fragment serves as both A and B.
__global__ __launch_bounds__(512)
void k_stats(const float* __restrict__ st, const float* __restrict__ dv,
             float* __restrict__ S){
    __shared__ float lds[8*SLAB];
    const int t = threadIdx.x, lane = t & 63, w = t >> 6;
    const int lo = lane & 15, hi = lane >> 4;
    float* slab = &lds[w*SLAB];
    const int gw = blockIdx.x*8 + w;           // 0..4095

    short8v ones;
    {
        short ov = (lo == 0) ? (short)0x3F80 : (short)0;
        #pragma unroll
        for (int i=0;i<8;++i) ones[i] = ov;
    }
    f32x4 a00 = (f32x4){0.f,0.f,0.f,0.f};
    f32x4 a01 = a00, a11 = a00, s0 = a00, s1 = a00;

    const int lp = lane >> 3, lq = lane & 7;
    const float* lbase = (lq < 4) ? st : dv;
    const int lch = (lq & 3) * 4;
    const size_t p0 = (size_t)gw * (KPW*32);

    float4 v[4];
    #pragma unroll
    for (int j2=0;j2<4;++j2)
        v[j2] = *(const float4*)&lbase[(p0 + lp + 8*j2)*CH + lch];

    #pragma unroll
    for (int j=0;j<KPW;++j){
        // stage current 32px x 32ch tile (stride 34 -> 2-way banks on reads, free)
        #pragma unroll
        for (int j2=0;j2<4;++j2){
            int p = lp + 8*j2;
            *(float2*)&slab[p*34 + lq*4]     = make_float2(v[j2].x, v[j2].y);
            *(float2*)&slab[p*34 + lq*4 + 2] = make_float2(v[j2].z, v[j2].w);
        }
        if (j+1 < KPW){
            const size_t pn = p0 + (size_t)(j+1)*32;
            #pragma unroll
            for (int j2=0;j2<4;++j2)
                v[j2] = *(const float4*)&lbase[(pn + lp + 8*j2)*CH + lch];
        }
        // fragment: lane -> channel (lo), k -> pixel (hi*8+i); truncation hi/lo split
        short8v r0h, r0l, r1h, r1l;
        #pragma unroll
        for (int ct=0;ct<2;++ct){
            #pragma unroll
            for (int i=0;i<8;++i){
                float f = slab[(hi*8+i)*34 + ct*16 + lo];
                unsigned int u = __float_as_uint(f);
                unsigned short ah = (unsigned short)(u >> 16);
                float r = f - __uint_as_float(u & 0xFFFF0000u);
                unsigned short al = (unsigned short)(__float_as_uint(r) >> 16);
                if (ct==0){ r0h[i]=(short)ah; r0l[i]=(short)al; }
                else      { r1h[i]=(short)ah; r1l[i]=(short)al; }
            }
        }
        s0 = __builtin_amdgcn_mfma_f32_16x16x32_bf16(ones, r0h, s0, 0,0,0);
        s0 = __builtin_amdgcn_mfma_f32_16x16x32_bf16(ones, r0l, s0, 0,0,0);
        s1 = __builtin_amdgcn_mfma_f32_16x16x32_bf16(ones, r1h, s1, 0,0,0);
        s1 = __builtin_amdgcn_mfma_f32_16x16x32_bf16(ones, r1l, s1, 0,0,0);
        a00 = __builtin_amdgcn_mfma_f32_16x16x32_bf16(r0h, r0h, a00, 0,0,0);
        a00 = __builtin_amdgcn_mfma_f32_16x16x32_bf16(r0l, r0h, a00, 0,0,0);
        a00 = __builtin_amdgcn_mfma_f32_16x16x32_bf16(r0h, r0l, a00, 0,0,0);
        a11 = __builtin_amdgcn_mfma_f32_16x16x32_bf16(r1h, r1h, a11, 0,0,0);
        a11 = __builtin_amdgcn_mfma_f32_16x16x32_bf16(r1l, r1h, a11, 0,0,0);
        a11 = __builtin_amdgcn_mfma_f32_16x16x32_bf16(r1h, r1l, a11, 0,0,0);
        a01 = __builtin_amdgcn_mfma_f32_16x16x32_bf16(r0h, r1h, a01, 0,0,0);
        a01 = __builtin_amdgcn_mfma_f32_16x16x32_bf16(r0l, r1h, a01, 0,0,0);
        a01 = __builtin_amdgcn_mfma_f32_16x16x32_bf16(r0h, r1l, a01, 0,0,0);
    }

    // block reduction: each wave writes into its own slab region, then wave 0 sums
    float* red = lds;
    #pragma unroll
    for (int k=0;k<4;++k){
        red[t*20 + k]      = a00[k];
        red[t*20 + 4 + k]  = a01[k];
        red[t*20 + 8 + k]  = a11[k];
        red[t*20 + 12 + k] = s0[k];
        red[t*20 + 16 + k] = s1[k];
    }
    __syncthreads();
    if (w == 0){
        float tmp[20];
        #pragma unroll
        for (int k=0;k<20;++k){
            float s = 0.f;
            #pragma unroll
            for (int ww=0;ww<8;++ww) s += red[(lane + 64*ww)*20 + k];
            tmp[k] = s;
        }
        #pragma unroll
        for (int r=0;r<4;++r){
            atomicAdd(&S[(hi*4+r)*32 + lo],        tmp[r]);
            atomicAdd(&S[(hi*4+r)*32 + 16 + lo],   tmp[4+r]);
            atomicAdd(&S[(16+lo)*32 + hi*4 + r],   tmp[4+r]);
            atomicAdd(&S[(16+hi*4+r)*32 + 16+lo],  tmp[8+r]);
        }
        if (hi == 0){
            atomicAdd(&S[1024 + lo],      tmp[12]);
            atomicAdd(&S[1024 + 16 + lo], tmp[16]);
        }
    }
}

__global__ void k_finalize(const float* __restrict__ S,
                           const float* __restrict__ w0, const float* __restrict__ b0,
                           const float* __restrict__ gam, const float* __restrict__ bet,
                           float* __restrict__ sc, float* __restrict__ sh){
    int o = threadIdx.x;
    const float inv = 1.f / (float)NPX;
    float w[32];
    #pragma unroll
    for (int c=0;c<32;++c) w[c] = w0[o*32+c];
    const float* su = S + 1024;
    float m1 = 0.f;
    #pragma unroll
    for (int c=0;c<32;++c) m1 += w[c]*su[c];
    m1 *= inv;
    float q = 0.f;
    for (int i=0;i<32;++i){
        float ti = 0.f;
        #pragma unroll
        for (int j=0;j<32;++j) ti += S[i*32+j]*w[j];
        q += w[i]*ti;
    }
    q *= inv;
    float var = q - m1*m1;
    float rstd = rsqrtf(var + 1e-5f);
    float mean = m1 + b0[o];
    float scale = rstd * gam[o];
    sc[o] = scale;
    sh[o] = bet[o] + (b0[o] - mean)*scale;
}

// MFMA update: fc0 (hi/lo split bf16) -> BN/relu -> LDS transpose -> fc1 -> masked residual
__global__ __launch_bounds__(256)
void k_update(const float* __restrict__ st, const float* __restrict__ dv,
              const int* __restrict__ msk,
              const unsigned short* __restrict__ gb0h, const unsigned short* __restrict__ gb0l,
              const unsigned short* __restrict__ gb1h, const unsigned short* __restrict__ gb1l,
              const float* __restrict__ sc, const float* __restrict__ sh,
              float* __restrict__ out){
    __shared__ float hbuf[4*16*132];
    const int lane = threadIdx.x & 63, w = threadIdx.x >> 6;
    const int lo16 = lane & 15, qw = lane >> 4;
    float* hb = &hbuf[w*16*132];

    const short8v* p0h = (const short8v*)gb0h;
    const short8v* p0l = (const short8v*)gb0l;
    const short8v* p1h = (const short8v*)gb1h;
    const short8v* p1l = (const short8v*)gb1l;
    short8v B0h[8], B0l[8], B1h[4], B1l[4];
    #pragma unroll
    for (int n=0;n<8;++n){ B0h[n] = p0h[n*64 + lane]; B0l[n] = p0l[n*64 + lane]; }
    #pragma unroll
    for (int tt=0;tt<4;++tt){ B1h[tt] = p1h[tt*64 + lane]; B1l[tt] = p1l[tt*64 + lane]; }
    float scr[8], shr[8];
    #pragma unroll
    for (int n=0;n<8;++n){ scr[n] = sc[16*n + lo16]; shr[n] = sh[16*n + lo16]; }

    const int gw = blockIdx.x*4 + w;
    const float* abase = (qw < 2) ? st : dv;
    const int choff = (qw & 1)*8;

    for (int gi = 0; gi < GPW; ++gi){
        const size_t pg0 = ((size_t)gw*GPW + gi)*16;
        const float* ap = abase + (pg0 + lo16)*CH + choff;
        float4 v0 = *(const float4*)ap;
        float4 v1 = *(const float4*)(ap + 4);
        float av[8] = {v0.x,v0.y,v0.z,v0.w,v1.x,v1.y,v1.z,v1.w};
        short8v ah, al;
        #pragma unroll
        for (int i=0;i<8;++i){
            unsigned short hi = f2bf(av[i]);
            ah[i] = (short)hi;
            al[i] = (short)f2bf(av[i] - bf2f(hi));
        }
        f32x4 acc[8];
        #pragma unroll
        for (int n=0;n<8;++n) acc[n] = (f32x4){0.f,0.f,0.f,0.f};
        #pragma unroll
        for (int n=0;n<8;++n){
            acc[n] = __builtin_amdgcn_mfma_f32_16x16x32_bf16(ah, B0h[n], acc[n], 0,0,0);
            acc[n] = __builtin_amdgcn_mfma_f32_16x16x32_bf16(al, B0h[n], acc[n], 0,0,0);
            acc[n] = __builtin_amdgcn_mfma_f32_16x16x32_bf16(ah, B0l[n], acc[n], 0,0,0);
        }
        #pragma unroll
        for (int n=0;n<8;++n){
            #pragma unroll
            for (int r=0;r<4;++r){
                float hp = fmaxf(acc[n][r]*scr[n] + shr[n], 0.f);
                hb[(qw*4 + r)*132 + 16*n + lo16] = hp;
            }
        }
        f32x4 dacc = (f32x4){0.f,0.f,0.f,0.f};
        #pragma unroll
        for (int tt=0;tt<4;++tt){
            const float* rp = &hb[lo16*132 + qw*8 + 32*tt];
            float4 h0 = *(const float4*)rp;
            float4 h1 = *(const float4*)(rp + 4);
            float hv[8] = {h0.x,h0.y,h0.z,h0.w,h1.x,h1.y,h1.z,h1.w};
            short8v ah2, al2;
            #pragma unroll
            for (int i=0;i<8;++i){
                unsigned short hi = f2bf(hv[i]);
                ah2[i] = (short)hi;
                al2[i] = (short)f2bf(hv[i] - bf2f(hi));
            }
            dacc = __builtin_amdgcn_mfma_f32_16x16x32_bf16(ah2, B1h[tt], dacc, 0,0,0);
            dacc = __builtin_amdgcn_mfma_f32_16x16x32_bf16(al2, B1h[tt], dacc, 0,0,0);
            dacc = __builtin_amdgcn_mfma_f32_16x16x32_bf16(ah2, B1l[tt], dacc, 0,0,0);
        }
        #pragma unroll
        for (int r=0;r<4;++r){
            const size_t p = pg0 + qw*4 + r;
            float stv = st[p*CH + lo16];
            float m = (float)msk[p];
            out[p*CH + lo16] = stv + dacc[r]*m;
        }
    }
}

extern "C" void kernel_launch(void* const* d_in, const int* in_sizes, int n_in,
                              void* d_out, int out_size, void* d_ws, size_t ws_size,
                              hipStream_t stream){
    const float* x   = (const float*)d_in[0];
    const int*   mk  = (const int*)d_in[1];
    const float* cw  = (const float*)d_in[2];
    const float* cb  = (const float*)d_in[3];
    const float* w0  = (const float*)d_in[4];
    const float* b0  = (const float*)d_in[5];
    const float* f1  = (const float*)d_in[6];
    const float* gam = (const float*)d_in[7];
    const float* bet = (const float*)d_in[8];

    float* ws    = (float*)d_ws;
    float* dbuf  = ws;                          // NPX*CH
    float* sbuf  = ws + (size_t)NPX*CH;         // NPX*CH
    float* stats = ws + (size_t)2*NPX*CH;       // NSTEP*STEPSTATS
    float* wp    = stats + NSTEP*STEPSTATS;     // 800
    unsigned short* b0h = (unsigned short*)(wp + 800);
    unsigned short* b0l = b0h + 4096;
    unsigned short* b1h = b0l + 4096;
    unsigned short* b1l = b1h + 2048;

    k_repack<<<16,256,0,stream>>>(cw, f1, w0, wp, b0h, b0l, b1h, b1l);
    k_zero<<<(NSTEP*STEPSTATS+255)/256,256,0,stream>>>(stats, NSTEP*STEPSTATS);

    const float* cur = x;
    float* outp = (float*)d_out;
    for (int s=0;s<NSTEP;++s){
        float* S  = stats + (size_t)s*STEPSTATS;
        float* sc = S + 1056;
        float* sh = S + 1184;
        float* nxt = (s & 1) ? outp : sbuf;     // s=9 lands in d_out
        k_conv<<<dim3(NW/TILE,NH/TILE,NB*2),256,0,stream>>>(cur, wp, cb, dbuf);
        k_stats<<<512,512,0,stream>>>(cur, dbuf, S);
        k_finalize<<<1,128,0,stream>>>(S, w0, b0, gam, bet, sc, sh);
        k_update<<<NPX/16/4/GPW,256,0,stream>>>(cur, dbuf, mk + (size_t)s*NPX,
                                                b0h, b0l, b1h, b1l, sc, sh, nxt);
        cur = nxt;
    }
}

// Round 4
// 1238.100 us; speedup vs baseline: 2.2325x; 1.2244x over previous
//
#include <hip/hip_runtime.h>

#define CH 16
#define HID 128
#define NB 8
#define NH 256
#define NW 256
#define NPX (NB*NH*NW)
#define NSTEP 10
#define STEPSTATS 1536
#define GPW 8
#define KPW 4
#define SLAB 1280

typedef __attribute__((ext_vector_type(8))) short short8v;
typedef __attribute__((ext_vector_type(4))) float f32x4;

__device__ __forceinline__ int refl(int i, int n){
    if (i < 0) i = -i;
    if (i >= n) i = 2*n - 2 - i;
    return i;
}

__device__ __forceinline__ unsigned short f2bf(float x){
    unsigned int u = __float_as_uint(x);
    u += 0x7FFFu + ((u >> 16) & 1u);
    return (unsigned short)(u >> 16);
}
__device__ __forceinline__ float bf2f(unsigned short h){
    return __uint_as_float(((unsigned int)h) << 16);
}

// wp[tap][c]; b0 frags: [n][lane][i] for W0^T tiles; b1 frags: [t][lane][i] for F1^T (col0 = 0 pad)
__global__ void k_repack(const float* __restrict__ cw, const float* __restrict__ f1,
                         const float* __restrict__ w0, float* __restrict__ wp,
                         unsigned short* __restrict__ b0h, unsigned short* __restrict__ b0l,
                         unsigned short* __restrict__ b1h, unsigned short* __restrict__ b1l){
    int t = blockIdx.x*256 + threadIdx.x;
    if (t < 49*16){ int tap = t >> 4, c = t & 15; wp[tap*16 + c] = cw[c*49 + tap]; }
    if (t < 4096){
        int n = t >> 9, l = (t >> 3) & 63, i = t & 7;
        int o = 16*n + (l & 15), k = ((l >> 4) << 3) + i;
        float v = w0[o*32 + k];
        unsigned short hi = f2bf(v);
        b0h[t] = hi;
        b0l[t] = f2bf(v - bf2f(hi));
    }
    if (t < 2048){
        int tk = t >> 9, l = (t >> 3) & 63, i = t & 7;
        int c = l & 15, k = tk*32 + ((l >> 4) << 3) + i;
        float v = (c >= 1) ? f1[(c-1)*HID + k] : 0.f;
        unsigned short hi = f2bf(v);
        b1h[t] = hi;
        b1l[t] = f2bf(v - bf2f(hi));
    }
}

__global__ void k_zero(float* __restrict__ p, int n){
    int t = blockIdx.x*256 + threadIdx.x;
    if (t < n) p[t] = 0.f;
}

// ---- conv: 32x32 px tile, 4-ch group, thread = 2x2 quad, even/odd column planes ----
struct Row { float4 e[4]; float4 o[4]; };

__device__ __forceinline__ void fma4(float4& a, float4 w, float4 v){
    a.x += w.x*v.x; a.y += w.y*v.y; a.z += w.z*v.z; a.w += w.w*v.w;
}
__device__ __forceinline__ void ldrow(Row& r, const float4* L, int row, int tx){
    #pragma unroll
    for (int k=0;k<4;++k){
        r.e[k] = L[(row*2+0)*20 + tx + k];
        r.o[k] = L[(row*2+1)*20 + tx + k];
    }
}

__global__ __launch_bounds__(256,3)
void k_conv(const float* __restrict__ st, const float* __restrict__ wp,
            const float* __restrict__ cb, float* __restrict__ dout){
    __shared__ float4 tile4[38*2*20];
    __shared__ float4 cw4s[49];
    const int b = blockIdx.z >> 2, cg = blockIdx.z & 3;
    const int y0 = blockIdx.y*32, x0 = blockIdx.x*32;
    const int t = threadIdx.x;
    const int tx = t & 15, ty = t >> 4;

    if (t < 49) cw4s[t] = *(const float4*)&wp[t*16 + cg*4];
    for (int i = t; i < 38*38; i += 256){
        int py = i / 38, px = i - py*38;
        int gy = refl(y0 + py - 3, NH);
        int gx = refl(x0 + px - 3, NW);
        float4 v = *(const float4*)&st[(((size_t)b*NH + gy)*NW + gx)*CH + cg*4];
        tile4[(py*2 + (px&1))*20 + (px>>1)] = v;
    }
    __syncthreads();

    const float4* L = tile4;
    float4 bias = *(const float4*)&cb[cg*4];
    float4 a00 = bias, a01 = bias, a10 = bias, a11 = bias;
    Row A, B;
    ldrow(A, L, 2*ty,   tx);
    ldrow(B, L, 2*ty+1, tx);

#define CSTEP(dy, RA, RB, LOADNEXT, NR) \
    { \
        _Pragma("unroll") \
        for (int dx = 0; dx < 7; ++dx){ \
            float4 w4 = cw4s[(dy)*7 + dx]; \
            float4 v00 = ((dx)&1)   ? RA.o[(dx)>>1]   : RA.e[(dx)>>1]; \
            float4 v01 = ((dx+1)&1) ? RA.o[(dx+1)>>1] : RA.e[(dx+1)>>1]; \
            float4 v10 = ((dx)&1)   ? RB.o[(dx)>>1]   : RB.e[(dx)>>1]; \
            float4 v11 = ((dx+1)&1) ? RB.o[(dx+1)>>1] : RB.e[(dx+1)>>1]; \
            fma4(a00,w4,v00); fma4(a01,w4,v01); fma4(a10,w4,v10); fma4(a11,w4,v11); \
        } \
        if (LOADNEXT) ldrow(RA, L, NR, tx); \
    }

    CSTEP(0, A, B, 1, 2*ty+2)
    CSTEP(1, B, A, 1, 2*ty+3)
    CSTEP(2, A, B, 1, 2*ty+4)
    CSTEP(3, B, A, 1, 2*ty+5)
    CSTEP(4, A, B, 1, 2*ty+6)
    CSTEP(5, B, A, 1, 2*ty+7)
    CSTEP(6, A, B, 0, 0)
#undef CSTEP

    const size_t pr = ((size_t)b*NH + (size_t)(y0 + 2*ty))*NW + (x0 + 2*tx);
    *(float4*)&dout[(pr)*CH + cg*4]        = a00;
    *(float4*)&dout[(pr+1)*CH + cg*4]      = a01;
    *(float4*)&dout[(pr+NW)*CH + cg*4]     = a10;
    *(float4*)&dout[(pr+NW+1)*CH + cg*4]   = a11;
}

// MFMA second moments: S = cat^T cat over pixels (3 unique 16x16 tiles, hi/lo split)
// plus channel sums via ones-row A-fragment. One fragment serves as both A and B.
__global__ __launch_bounds__(512)
void k_stats(const float* __restrict__ st, const float* __restrict__ dv,
             float* __restrict__ S){
    __shared__ float lds[8*SLAB];
    const int t = threadIdx.x, lane = t & 63, w = t >> 6;
    const int lo = lane & 15, hi = lane >> 4;
    float* slab = &lds[w*SLAB];
    const int gw = blockIdx.x*8 + w;           // 0..4095

    short8v ones;
    {
        short ov = (lo == 0) ? (short)0x3F80 : (short)0;
        #pragma unroll
        for (int i=0;i<8;++i) ones[i] = ov;
    }
    f32x4 a00 = (f32x4){0.f,0.f,0.f,0.f};
    f32x4 a01 = a00, a11 = a00, s0 = a00, s1 = a00;

    const int lp = lane >> 3, lq = lane & 7;
    const float* lbase = (lq < 4) ? st : dv;
    const int lch = (lq & 3) * 4;
    const size_t p0 = (size_t)gw * (KPW*32);

    float4 v[4];
    #pragma unroll
    for (int j2=0;j2<4;++j2)
        v[j2] = *(const float4*)&lbase[(p0 + lp + 8*j2)*CH + lch];

    #pragma unroll
    for (int j=0;j<KPW;++j){
        #pragma unroll
        for (int j2=0;j2<4;++j2){
            int p = lp + 8*j2;
            *(float2*)&slab[p*34 + lq*4]     = make_float2(v[j2].x, v[j2].y);
            *(float2*)&slab[p*34 + lq*4 + 2] = make_float2(v[j2].z, v[j2].w);
        }
        if (j+1 < KPW){
            const size_t pn = p0 + (size_t)(j+1)*32;
            #pragma unroll
            for (int j2=0;j2<4;++j2)
                v[j2] = *(const float4*)&lbase[(pn + lp + 8*j2)*CH + lch];
        }
        short8v r0h, r0l, r1h, r1l;
        #pragma unroll
        for (int ct=0;ct<2;++ct){
            #pragma unroll
            for (int i=0;i<8;++i){
                float f = slab[(hi*8+i)*34 + ct*16 + lo];
                unsigned int u = __float_as_uint(f);
                unsigned short ah = (unsigned short)(u >> 16);
                float r = f - __uint_as_float(u & 0xFFFF0000u);
                unsigned short al = (unsigned short)(__float_as_uint(r) >> 16);
                if (ct==0){ r0h[i]=(short)ah; r0l[i]=(short)al; }
                else      { r1h[i]=(short)ah; r1l[i]=(short)al; }
            }
        }
        s0 = __builtin_amdgcn_mfma_f32_16x16x32_bf16(ones, r0h, s0, 0,0,0);
        s0 = __builtin_amdgcn_mfma_f32_16x16x32_bf16(ones, r0l, s0, 0,0,0);
        s1 = __builtin_amdgcn_mfma_f32_16x16x32_bf16(ones, r1h, s1, 0,0,0);
        s1 = __builtin_amdgcn_mfma_f32_16x16x32_bf16(ones, r1l, s1, 0,0,0);
        a00 = __builtin_amdgcn_mfma_f32_16x16x32_bf16(r0h, r0h, a00, 0,0,0);
        a00 = __builtin_amdgcn_mfma_f32_16x16x32_bf16(r0l, r0h, a00, 0,0,0);
        a00 = __builtin_amdgcn_mfma_f32_16x16x32_bf16(r0h, r0l, a00, 0,0,0);
        a11 = __builtin_amdgcn_mfma_f32_16x16x32_bf16(r1h, r1h, a11, 0,0,0);
        a11 = __builtin_amdgcn_mfma_f32_16x16x32_bf16(r1l, r1h, a11, 0,0,0);
        a11 = __builtin_amdgcn_mfma_f32_16x16x32_bf16(r1h, r1l, a11, 0,0,0);
        a01 = __builtin_amdgcn_mfma_f32_16x16x32_bf16(r0h, r1h, a01, 0,0,0);
        a01 = __builtin_amdgcn_mfma_f32_16x16x32_bf16(r0l, r1h, a01, 0,0,0);
        a01 = __builtin_amdgcn_mfma_f32_16x16x32_bf16(r0h, r1l, a01, 0,0,0);
    }

    float* red = lds;
    #pragma unroll
    for (int k=0;k<4;++k){
        red[t*20 + k]      = a00[k];
        red[t*20 + 4 + k]  = a01[k];
        red[t*20 + 8 + k]  = a11[k];
        red[t*20 + 12 + k] = s0[k];
        red[t*20 + 16 + k] = s1[k];
    }
    __syncthreads();
    if (w == 0){
        float tmp[20];
        #pragma unroll
        for (int k=0;k<20;++k){
            float s = 0.f;
            #pragma unroll
            for (int ww=0;ww<8;++ww) s += red[(lane + 64*ww)*20 + k];
            tmp[k] = s;
        }
        #pragma unroll
        for (int r=0;r<4;++r){
            atomicAdd(&S[(hi*4+r)*32 + lo],        tmp[r]);
            atomicAdd(&S[(hi*4+r)*32 + 16 + lo],   tmp[4+r]);
            atomicAdd(&S[(16+lo)*32 + hi*4 + r],   tmp[4+r]);
            atomicAdd(&S[(16+hi*4+r)*32 + 16+lo],  tmp[8+r]);
        }
        if (hi == 0){
            atomicAdd(&S[1024 + lo],      tmp[12]);
            atomicAdd(&S[1024 + 16 + lo], tmp[16]);
        }
    }
}

__global__ void k_finalize(const float* __restrict__ S,
                           const float* __restrict__ w0, const float* __restrict__ b0,
                           const float* __restrict__ gam, const float* __restrict__ bet,
                           float* __restrict__ sc, float* __restrict__ sh){
    int o = threadIdx.x;
    const float inv = 1.f / (float)NPX;
    float w[32];
    #pragma unroll
    for (int c=0;c<32;++c) w[c] = w0[o*32+c];
    const float* su = S + 1024;
    float m1 = 0.f;
    #pragma unroll
    for (int c=0;c<32;++c) m1 += w[c]*su[c];
    m1 *= inv;
    float q = 0.f;
    for (int i=0;i<32;++i){
        float ti = 0.f;
        #pragma unroll
        for (int j=0;j<32;++j) ti += S[i*32+j]*w[j];
        q += w[i]*ti;
    }
    q *= inv;
    float var = q - m1*m1;
    float rstd = rsqrtf(var + 1e-5f);
    float mean = m1 + b0[o];
    float scale = rstd * gam[o];
    sc[o] = scale;
    sh[o] = bet[o] + (b0[o] - mean)*scale;
}

// MFMA update: fc0 (hi/lo split bf16) -> BN/relu -> LDS transpose -> fc1 -> masked residual
__global__ __launch_bounds__(256)
void k_update(const float* __restrict__ st, const float* __restrict__ dv,
              const int* __restrict__ msk,
              const unsigned short* __restrict__ gb0h, const unsigned short* __restrict__ gb0l,
              const unsigned short* __restrict__ gb1h, const unsigned short* __restrict__ gb1l,
              const float* __restrict__ sc, const float* __restrict__ sh,
              float* __restrict__ out){
    __shared__ float hbuf[4*16*132];
    const int lane = threadIdx.x & 63, w = threadIdx.x >> 6;
    const int lo16 = lane & 15, qw = lane >> 4;
    float* hb = &hbuf[w*16*132];

    const short8v* p0h = (const short8v*)gb0h;
    const short8v* p0l = (const short8v*)gb0l;
    const short8v* p1h = (const short8v*)gb1h;
    const short8v* p1l = (const short8v*)gb1l;
    short8v B0h[8], B0l[8], B1h[4], B1l[4];
    #pragma unroll
    for (int n=0;n<8;++n){ B0h[n] = p0h[n*64 + lane]; B0l[n] = p0l[n*64 + lane]; }
    #pragma unroll
    for (int tt=0;tt<4;++tt){ B1h[tt] = p1h[tt*64 + lane]; B1l[tt] = p1l[tt*64 + lane]; }
    float scr[8], shr[8];
    #pragma unroll
    for (int n=0;n<8;++n){ scr[n] = sc[16*n + lo16]; shr[n] = sh[16*n + lo16]; }

    const int gw = blockIdx.x*4 + w;
    const float* abase = (qw < 2) ? st : dv;
    const int choff = (qw & 1)*8;

    for (int gi = 0; gi < GPW; ++gi){
        const size_t pg0 = ((size_t)gw*GPW + gi)*16;
        const float* ap = abase + (pg0 + lo16)*CH + choff;
        float4 v0 = *(const float4*)ap;
        float4 v1 = *(const float4*)(ap + 4);
        float av[8] = {v0.x,v0.y,v0.z,v0.w,v1.x,v1.y,v1.z,v1.w};
        short8v ah, al;
        #pragma unroll
        for (int i=0;i<8;++i){
            unsigned short hi = f2bf(av[i]);
            ah[i] = (short)hi;
            al[i] = (short)f2bf(av[i] - bf2f(hi));
        }
        f32x4 acc[8];
        #pragma unroll
        for (int n=0;n<8;++n) acc[n] = (f32x4){0.f,0.f,0.f,0.f};
        #pragma unroll
        for (int n=0;n<8;++n){
            acc[n] = __builtin_amdgcn_mfma_f32_16x16x32_bf16(ah, B0h[n], acc[n], 0,0,0);
            acc[n] = __builtin_amdgcn_mfma_f32_16x16x32_bf16(al, B0h[n], acc[n], 0,0,0);
            acc[n] = __builtin_amdgcn_mfma_f32_16x16x32_bf16(ah, B0l[n], acc[n], 0,0,0);
        }
        #pragma unroll
        for (int n=0;n<8;++n){
            #pragma unroll
            for (int r=0;r<4;++r){
                float hp = fmaxf(acc[n][r]*scr[n] + shr[n], 0.f);
                hb[(qw*4 + r)*132 + 16*n + lo16] = hp;
            }
        }
        f32x4 dacc = (f32x4){0.f,0.f,0.f,0.f};
        #pragma unroll
        for (int tt=0;tt<4;++tt){
            const float* rp = &hb[lo16*132 + qw*8 + 32*tt];
            float4 h0 = *(const float4*)rp;
            float4 h1 = *(const float4*)(rp + 4);
            float hv[8] = {h0.x,h0.y,h0.z,h0.w,h1.x,h1.y,h1.z,h1.w};
            short8v ah2, al2;
            #pragma unroll
            for (int i=0;i<8;++i){
                unsigned short hi = f2bf(hv[i]);
                ah2[i] = (short)hi;
                al2[i] = (short)f2bf(hv[i] - bf2f(hi));
            }
            dacc = __builtin_amdgcn_mfma_f32_16x16x32_bf16(ah2, B1h[tt], dacc, 0,0,0);
            dacc = __builtin_amdgcn_mfma_f32_16x16x32_bf16(al2, B1h[tt], dacc, 0,0,0);
            dacc = __builtin_amdgcn_mfma_f32_16x16x32_bf16(ah2, B1l[tt], dacc, 0,0,0);
        }
        #pragma unroll
        for (int r=0;r<4;++r){
            const size_t p = pg0 + qw*4 + r;
            float stv = st[p*CH + lo16];
            float m = (float)msk[p];
            out[p*CH + lo16] = stv + dacc[r]*m;
        }
    }
}

extern "C" void kernel_launch(void* const* d_in, const int* in_sizes, int n_in,
                              void* d_out, int out_size, void* d_ws, size_t ws_size,
                              hipStream_t stream){
    const float* x   = (const float*)d_in[0];
    const int*   mk  = (const int*)d_in[1];
    const float* cw  = (const float*)d_in[2];
    const float* cb  = (const float*)d_in[3];
    const float* w0  = (const float*)d_in[4];
    const float* b0  = (const float*)d_in[5];
    const float* f1  = (const float*)d_in[6];
    const float* gam = (const float*)d_in[7];
    const float* bet = (const float*)d_in[8];

    float* ws    = (float*)d_ws;
    float* dbuf  = ws;                          // NPX*CH
    float* sbuf  = ws + (size_t)NPX*CH;         // NPX*CH
    float* stats = ws + (size_t)2*NPX*CH;       // NSTEP*STEPSTATS
    float* wp    = stats + NSTEP*STEPSTATS;     // 800
    unsigned short* b0h = (unsigned short*)(wp + 800);
    unsigned short* b0l = b0h + 4096;
    unsigned short* b1h = b0l + 4096;
    unsigned short* b1l = b1h + 2048;

    k_repack<<<16,256,0,stream>>>(cw, f1, w0, wp, b0h, b0l, b1h, b1l);
    k_zero<<<(NSTEP*STEPSTATS+255)/256,256,0,stream>>>(stats, NSTEP*STEPSTATS);

    const float* cur = x;
    float* outp = (float*)d_out;
    for (int s=0;s<NSTEP;++s){
        float* S  = stats + (size_t)s*STEPSTATS;
        float* sc = S + 1056;
        float* sh = S + 1184;
        float* nxt = (s & 1) ? outp : sbuf;     // s=9 lands in d_out
        k_conv<<<dim3(NW/32,NH/32,NB*4),256,0,stream>>>(cur, wp, cb, dbuf);
        k_stats<<<512,512,0,stream>>>(cur, dbuf, S);
        k_finalize<<<1,128,0,stream>>>(S, w0, b0, gam, bet, sc, sh);
        k_update<<<NPX/16/4/GPW,256,0,stream>>>(cur, dbuf, mk + (size_t)s*NPX,
                                                b0h, b0l, b1h, b1l, sc, sh, nxt);
        cur = nxt;
    }
}

// Round 5
// 1085.201 us; speedup vs baseline: 2.5470x; 1.1409x over previous
//
#include <hip/hip_runtime.h>

#define CH 16
#define HID 128
#define NB 8
#define NH 256
#define NW 256
#define NPX (NB*NH*NW)
#define NSTEP 10
#define STEPSTATS 2240
#define GPW 8
#define KPW 4
#define SLAB 1280

typedef __attribute__((ext_vector_type(8))) short short8v;
typedef __attribute__((ext_vector_type(4))) float f32x4;

__device__ __forceinline__ int refl(int i, int n){
    if (i < 0) i = -i;
    if (i >= n) i = 2*n - 2 - i;
    return i;
}

__device__ __forceinline__ unsigned short f2bf(float x){
    unsigned int u = __float_as_uint(x);
    u += 0x7FFFu + ((u >> 16) & 1u);
    return (unsigned short)(u >> 16);
}
__device__ __forceinline__ float bf2f(unsigned short h){
    return __uint_as_float(((unsigned int)h) << 16);
}
__device__ __forceinline__ unsigned int cvtpk(float lo, float hi){
    unsigned int r;
    asm("v_cvt_pk_bf16_f32 %0, %1, %2" : "=v"(r) : "v"(lo), "v"(hi));
    return r;
}

// wp[tap][c]; b0 frags: [n][lane][i] -> W0 tiles (lane&15 = hidden-within-16, k = cat channel)
__global__ void k_repack(const float* __restrict__ cw, const float* __restrict__ w0,
                         float* __restrict__ wp,
                         unsigned short* __restrict__ b0h, unsigned short* __restrict__ b0l){
    int t = blockIdx.x*256 + threadIdx.x;
    if (t < 49*16){ int tap = t >> 4, c = t & 15; wp[tap*16 + c] = cw[c*49 + tap]; }
    if (t < 4096){
        int n = t >> 9, l = (t >> 3) & 63, i = t & 7;
        int o = 16*n + (l & 15), k = ((l >> 4) << 3) + i;
        float v = w0[o*32 + k];
        unsigned short hi = f2bf(v);
        b0h[t] = hi;
        b0l[t] = f2bf(v - bf2f(hi));
    }
}

__global__ void k_zero(float* __restrict__ p, int n){
    int t = blockIdx.x*256 + threadIdx.x;
    if (t < n) p[t] = 0.f;
}

// ---- conv: 32x32 px tile, 4-ch group, thread = 2x2 quad, even/odd column planes ----
struct Row { float4 e[4]; float4 o[4]; };

__device__ __forceinline__ void fma4(float4& a, float4 w, float4 v){
    a.x += w.x*v.x; a.y += w.y*v.y; a.z += w.z*v.z; a.w += w.w*v.w;
}
__device__ __forceinline__ void ldrow(Row& r, const float4* L, int row, int tx){
    #pragma unroll
    for (int k=0;k<4;++k){
        r.e[k] = L[(row*2+0)*20 + tx + k];
        r.o[k] = L[(row*2+1)*20 + tx + k];
    }
}

__global__ __launch_bounds__(256,3)
void k_conv(const float* __restrict__ st, const float* __restrict__ wp,
            const float* __restrict__ cb, float* __restrict__ dout){
    __shared__ float4 tile4[38*2*20];
    __shared__ float4 cw4s[49];
    const int b = blockIdx.z >> 2, cg = blockIdx.z & 3;
    const int y0 = blockIdx.y*32, x0 = blockIdx.x*32;
    const int t = threadIdx.x;
    const int tx = t & 15, ty = t >> 4;

    if (t < 49) cw4s[t] = *(const float4*)&wp[t*16 + cg*4];
    for (int i = t; i < 38*38; i += 256){
        int py = i / 38, px = i - py*38;
        int gy = refl(y0 + py - 3, NH);
        int gx = refl(x0 + px - 3, NW);
        float4 v = *(const float4*)&st[(((size_t)b*NH + gy)*NW + gx)*CH + cg*4];
        tile4[(py*2 + (px&1))*20 + (px>>1)] = v;
    }
    __syncthreads();

    const float4* L = tile4;
    float4 bias = *(const float4*)&cb[cg*4];
    float4 a00 = bias, a01 = bias, a10 = bias, a11 = bias;
    Row A, B;
    ldrow(A, L, 2*ty,   tx);
    ldrow(B, L, 2*ty+1, tx);

#define CSTEP(dy, RA, RB, LOADNEXT, NR) \
    { \
        _Pragma("unroll") \
        for (int dx = 0; dx < 7; ++dx){ \
            float4 w4 = cw4s[(dy)*7 + dx]; \
            float4 v00 = ((dx)&1)   ? RA.o[(dx)>>1]   : RA.e[(dx)>>1]; \
            float4 v01 = ((dx+1)&1) ? RA.o[(dx+1)>>1] : RA.e[(dx+1)>>1]; \
            float4 v10 = ((dx)&1)   ? RB.o[(dx)>>1]   : RB.e[(dx)>>1]; \
            float4 v11 = ((dx+1)&1) ? RB.o[(dx+1)>>1] : RB.e[(dx+1)>>1]; \
            fma4(a00,w4,v00); fma4(a01,w4,v01); fma4(a10,w4,v10); fma4(a11,w4,v11); \
        } \
        if (LOADNEXT) ldrow(RA, L, NR, tx); \
    }

    CSTEP(0, A, B, 1, 2*ty+2)
    CSTEP(1, B, A, 1, 2*ty+3)
    CSTEP(2, A, B, 1, 2*ty+4)
    CSTEP(3, B, A, 1, 2*ty+5)
    CSTEP(4, A, B, 1, 2*ty+6)
    CSTEP(5, B, A, 1, 2*ty+7)
    CSTEP(6, A, B, 0, 0)
#undef CSTEP

    const size_t pr = ((size_t)b*NH + (size_t)(y0 + 2*ty))*NW + (x0 + 2*tx);
    *(float4*)&dout[(pr)*CH + cg*4]        = a00;
    *(float4*)&dout[(pr+1)*CH + cg*4]      = a01;
    *(float4*)&dout[(pr+NW)*CH + cg*4]     = a10;
    *(float4*)&dout[(pr+NW+1)*CH + cg*4]   = a11;
}

// MFMA second moments: S = cat^T cat over pixels (3 unique 16x16 tiles, hi/lo split)
// plus channel sums via ones-row A-fragment. One fragment serves as both A and B.
__global__ __launch_bounds__(512)
void k_stats(const float* __restrict__ st, const float* __restrict__ dv,
             float* __restrict__ S){
    __shared__ float lds[8*SLAB];
    const int t = threadIdx.x, lane = t & 63, w = t >> 6;
    const int lo = lane & 15, hi = lane >> 4;
    float* slab = &lds[w*SLAB];
    const int gw = blockIdx.x*8 + w;           // 0..4095

    short8v ones;
    {
        short ov = (lo == 0) ? (short)0x3F80 : (short)0;
        #pragma unroll
        for (int i=0;i<8;++i) ones[i] = ov;
    }
    f32x4 a00 = (f32x4){0.f,0.f,0.f,0.f};
    f32x4 a01 = a00, a11 = a00, s0 = a00, s1 = a00;

    const int lp = lane >> 3, lq = lane & 7;
    const float* lbase = (lq < 4) ? st : dv;
    const int lch = (lq & 3) * 4;
    const size_t p0 = (size_t)gw * (KPW*32);

    float4 v[4];
    #pragma unroll
    for (int j2=0;j2<4;++j2)
        v[j2] = *(const float4*)&lbase[(p0 + lp + 8*j2)*CH + lch];

    #pragma unroll
    for (int j=0;j<KPW;++j){
        #pragma unroll
        for (int j2=0;j2<4;++j2){
            int p = lp + 8*j2;
            *(float2*)&slab[p*34 + lq*4]     = make_float2(v[j2].x, v[j2].y);
            *(float2*)&slab[p*34 + lq*4 + 2] = make_float2(v[j2].z, v[j2].w);
        }
        if (j+1 < KPW){
            const size_t pn = p0 + (size_t)(j+1)*32;
            #pragma unroll
            for (int j2=0;j2<4;++j2)
                v[j2] = *(const float4*)&lbase[(pn + lp + 8*j2)*CH + lch];
        }
        short8v r0h, r0l, r1h, r1l;
        #pragma unroll
        for (int ct=0;ct<2;++ct){
            #pragma unroll
            for (int i=0;i<8;++i){
                float f = slab[(hi*8+i)*34 + ct*16 + lo];
                unsigned int u = __float_as_uint(f);
                unsigned short ah = (unsigned short)(u >> 16);
                float r = f - __uint_as_float(u & 0xFFFF0000u);
                unsigned short al = (unsigned short)(__float_as_uint(r) >> 16);
                if (ct==0){ r0h[i]=(short)ah; r0l[i]=(short)al; }
                else      { r1h[i]=(short)ah; r1l[i]=(short)al; }
            }
        }
        s0 = __builtin_amdgcn_mfma_f32_16x16x32_bf16(ones, r0h, s0, 0,0,0);
        s0 = __builtin_amdgcn_mfma_f32_16x16x32_bf16(ones, r0l, s0, 0,0,0);
        s1 = __builtin_amdgcn_mfma_f32_16x16x32_bf16(ones, r1h, s1, 0,0,0);
        s1 = __builtin_amdgcn_mfma_f32_16x16x32_bf16(ones, r1l, s1, 0,0,0);
        a00 = __builtin_amdgcn_mfma_f32_16x16x32_bf16(r0h, r0h, a00, 0,0,0);
        a00 = __builtin_amdgcn_mfma_f32_16x16x32_bf16(r0l, r0h, a00, 0,0,0);
        a00 = __builtin_amdgcn_mfma_f32_16x16x32_bf16(r0h, r0l, a00, 0,0,0);
        a11 = __builtin_amdgcn_mfma_f32_16x16x32_bf16(r1h, r1h, a11, 0,0,0);
        a11 = __builtin_amdgcn_mfma_f32_16x16x32_bf16(r1l, r1h, a11, 0,0,0);
        a11 = __builtin_amdgcn_mfma_f32_16x16x32_bf16(r1h, r1l, a11, 0,0,0);
        a01 = __builtin_amdgcn_mfma_f32_16x16x32_bf16(r0h, r1h, a01, 0,0,0);
        a01 = __builtin_amdgcn_mfma_f32_16x16x32_bf16(r0l, r1h, a01, 0,0,0);
        a01 = __builtin_amdgcn_mfma_f32_16x16x32_bf16(r0h, r1l, a01, 0,0,0);
    }

    float* red = lds;
    #pragma unroll
    for (int k=0;k<4;++k){
        red[t*20 + k]      = a00[k];
        red[t*20 + 4 + k]  = a01[k];
        red[t*20 + 8 + k]  = a11[k];
        red[t*20 + 12 + k] = s0[k];
        red[t*20 + 16 + k] = s1[k];
    }
    __syncthreads();
    if (w == 0){
        float tmp[20];
        #pragma unroll
        for (int k=0;k<20;++k){
            float s = 0.f;
            #pragma unroll
            for (int ww=0;ww<8;++ww) s += red[(lane + 64*ww)*20 + k];
            tmp[k] = s;
        }
        #pragma unroll
        for (int r=0;r<4;++r){
            atomicAdd(&S[(hi*4+r)*32 + lo],        tmp[r]);
            atomicAdd(&S[(hi*4+r)*32 + 16 + lo],   tmp[4+r]);
            atomicAdd(&S[(16+lo)*32 + hi*4 + r],   tmp[4+r]);
            atomicAdd(&S[(16+hi*4+r)*32 + 16+lo],  tmp[8+r]);
        }
        if (hi == 0){
            atomicAdd(&S[1024 + lo],      tmp[12]);
            atomicAdd(&S[1024 + 16 + lo], tmp[16]);
        }
    }
}

// BN fold: sc = rstd*gam > 0 (gam==1 at runtime), so relu(sc*x+sh) = sc*relu(x + sh/sc).
// Emits shb = sh/sc (MFMA C-init) and per-step f1s frags = f1 * sc (bf16, c=0 col zeroed).
__global__ void k_finalize(const float* __restrict__ S,
                           const float* __restrict__ w0, const float* __restrict__ b0,
                           const float* __restrict__ gam, const float* __restrict__ bet,
                           const float* __restrict__ f1, float* __restrict__ Sout){
    int o = threadIdx.x;
    const float inv = 1.f / (float)NPX;
    float w[32];
    #pragma unroll
    for (int c=0;c<32;++c) w[c] = w0[o*32+c];
    const float* su = S + 1024;
    float m1 = 0.f;
    #pragma unroll
    for (int c=0;c<32;++c) m1 += w[c]*su[c];
    m1 *= inv;
    float q = 0.f;
    for (int i=0;i<32;++i){
        float ti = 0.f;
        #pragma unroll
        for (int j=0;j<32;++j) ti += S[i*32+j]*w[j];
        q += w[i]*ti;
    }
    q *= inv;
    float var = q - m1*m1;
    float rstd = rsqrtf(var + 1e-5f);
    float mean = m1 + b0[o];
    float scale = rstd * gam[o];
    Sout[1056 + o] = bet[o]/scale + b0[o] - mean;   // shb
    unsigned short* f1sh = (unsigned short*)(Sout + 1184);
    const int base = (o>>5)*512 + ((o>>3)&3)*128 + (o&7);
    f1sh[base] = 0;                                  // out-ch 0 pad
    #pragma unroll
    for (int c=1;c<16;++c)
        f1sh[base + c*8] = f2bf(f1[(c-1)*HID + o] * scale);
}

// MFMA update, swapped operands: acc = shb + W0*cat (col=pixel,row=hidden) ->
// relu -> bf16-pack -> LDS -> GEMM2 frag read -> delta (col=pixel,row=channel) -> residual
__global__ __launch_bounds__(256)
void k_update(const float* __restrict__ st, const float* __restrict__ dv,
              const int* __restrict__ msk,
              const unsigned short* __restrict__ gb0h, const unsigned short* __restrict__ gb0l,
              const float* __restrict__ Sstep, float* __restrict__ out){
    __shared__ __align__(16) unsigned int hls[4*16*68];
    const int lane = threadIdx.x & 63, w = threadIdx.x >> 6;
    const int lo16 = lane & 15, qw = lane >> 4;
    unsigned int* hb = &hls[w*16*68];

    const short8v* p0h = (const short8v*)gb0h;
    const short8v* p0l = (const short8v*)gb0l;
    const short8v* p1h = (const short8v*)(Sstep + 1184);
    short8v B0h[8], B0l[8], B1h[4];
    #pragma unroll
    for (int n=0;n<8;++n){ B0h[n] = p0h[n*64 + lane]; B0l[n] = p0l[n*64 + lane]; }
    #pragma unroll
    for (int tt=0;tt<4;++tt) B1h[tt] = p1h[tt*64 + lane];
    const float* shb = Sstep + 1056;
    float4 shbv[8];
    #pragma unroll
    for (int n=0;n<8;++n) shbv[n] = *(const float4*)&shb[16*n + 4*qw];

    const int gw = blockIdx.x*4 + w;
    const float* abase = (qw < 2) ? st : dv;
    const int choff = (qw & 1)*8;

    for (int gi = 0; gi < GPW; ++gi){
        const size_t pg0 = ((size_t)gw*GPW + gi)*16;
        // cat B-fragment: lane = pixel (lo16), k = channel (qw*8+i); truncation hi/lo split
        const float* ap = abase + (pg0 + lo16)*CH + choff;
        float4 v0 = *(const float4*)ap;
        float4 v1 = *(const float4*)(ap + 4);
        float av[8] = {v0.x,v0.y,v0.z,v0.w,v1.x,v1.y,v1.z,v1.w};
        short8v ah, al;
        #pragma unroll
        for (int i=0;i<8;++i){
            unsigned int u = __float_as_uint(av[i]);
            ah[i] = (short)(unsigned short)(u >> 16);
            float r = av[i] - __uint_as_float(u & 0xFFFF0000u);
            al[i] = (short)(unsigned short)(__float_as_uint(r) >> 16);
        }
        f32x4 acc[8];
        #pragma unroll
        for (int n=0;n<8;++n)
            acc[n] = (f32x4){shbv[n].x, shbv[n].y, shbv[n].z, shbv[n].w};
        #pragma unroll
        for (int n=0;n<8;++n){
            acc[n] = __builtin_amdgcn_mfma_f32_16x16x32_bf16(B0h[n], ah, acc[n], 0,0,0);
            acc[n] = __builtin_amdgcn_mfma_f32_16x16x32_bf16(B0h[n], al, acc[n], 0,0,0);
            acc[n] = __builtin_amdgcn_mfma_f32_16x16x32_bf16(B0l[n], ah, acc[n], 0,0,0);
        }
        // relu + bf16 pack -> LDS (per-wave region; same-wave RAW ordered by waitcnt)
        #pragma unroll
        for (int n=0;n<8;++n){
            float h0 = fmaxf(acc[n][0], 0.f), h1 = fmaxf(acc[n][1], 0.f);
            float h2 = fmaxf(acc[n][2], 0.f), h3 = fmaxf(acc[n][3], 0.f);
            unsigned int wa = cvtpk(h0, h1), wb = cvtpk(h2, h3);
            *(uint2*)&hb[lo16*68 + 8*n + 2*qw] = make_uint2(wa, wb);
        }
        // GEMM2: A = f1s (m = out-ch), B = h (lane = pixel, k = hidden 32tt+8qw+i)
        f32x4 dacc = (f32x4){0.f,0.f,0.f,0.f};
        #pragma unroll
        for (int tt=0;tt<4;++tt){
            short8v ah2 = *(const short8v*)&hb[lo16*68 + 16*tt + 4*qw];
            dacc = __builtin_amdgcn_mfma_f32_16x16x32_bf16(B1h[tt], ah2, dacc, 0,0,0);
        }
        // epilogue: lane holds delta for channels 4qw..4qw+3 of pixel pg0+lo16
        const size_t p = pg0 + lo16;
        float4 stv = *(const float4*)&st[p*CH + 4*qw];
        const float m = (float)msk[p];
        float4 ov;
        ov.x = stv.x + dacc[0]*m;
        ov.y = stv.y + dacc[1]*m;
        ov.z = stv.z + dacc[2]*m;
        ov.w = stv.w + dacc[3]*m;
        *(float4*)&out[p*CH + 4*qw] = ov;
    }
}

extern "C" void kernel_launch(void* const* d_in, const int* in_sizes, int n_in,
                              void* d_out, int out_size, void* d_ws, size_t ws_size,
                              hipStream_t stream){
    const float* x   = (const float*)d_in[0];
    const int*   mk  = (const int*)d_in[1];
    const float* cw  = (const float*)d_in[2];
    const float* cb  = (const float*)d_in[3];
    const float* w0  = (const float*)d_in[4];
    const float* b0  = (const float*)d_in[5];
    const float* f1  = (const float*)d_in[6];
    const float* gam = (const float*)d_in[7];
    const float* bet = (const float*)d_in[8];

    float* ws    = (float*)d_ws;
    float* dbuf  = ws;                          // NPX*CH
    float* sbuf  = ws + (size_t)NPX*CH;         // NPX*CH
    float* stats = ws + (size_t)2*NPX*CH;       // NSTEP*STEPSTATS
    float* wp    = stats + NSTEP*STEPSTATS;     // 800
    unsigned short* b0h = (unsigned short*)(wp + 800);
    unsigned short* b0l = b0h + 4096;

    k_repack<<<16,256,0,stream>>>(cw, w0, wp, b0h, b0l);
    k_zero<<<(NSTEP*STEPSTATS+255)/256,256,0,stream>>>(stats, NSTEP*STEPSTATS);

    const float* cur = x;
    float* outp = (float*)d_out;
    for (int s=0;s<NSTEP;++s){
        float* S = stats + (size_t)s*STEPSTATS;
        float* nxt = (s & 1) ? outp : sbuf;     // s=9 lands in d_out
        k_conv<<<dim3(NW/32,NH/32,NB*4),256,0,stream>>>(cur, wp, cb, dbuf);
        k_stats<<<512,512,0,stream>>>(cur, dbuf, S);
        k_finalize<<<1,128,0,stream>>>(S, w0, b0, gam, bet, f1, S);
        k_update<<<NPX/16/4/GPW,256,0,stream>>>(cur, dbuf, mk + (size_t)s*NPX,
                                                b0h, b0l, S, nxt);
        cur = nxt;
    }
}